// Round 13
// baseline (434.974 us; speedup 1.0000x reference)
//
#include <hip/hip_runtime.h>
#include <stdint.h>

#define D 2560
#define NH 64
#define HD 40
#define TE_ 512
#define FFD 10240
#define TENC 128
#define THID 1024
#define SEQ 1152   // TENC + THID

typedef __bf16 bf16_t;
typedef __bf16 bf16x8 __attribute__((ext_vector_type(8)));
typedef float  f32x4  __attribute__((ext_vector_type(4)));

__device__ __forceinline__ void gld_lds16(const void* g, void* l) {
  __builtin_amdgcn_global_load_lds((__attribute__((address_space(1))) void*)(g),
                                   (__attribute__((address_space(3))) void*)(l), 16, 0, 0);
}

// ---------------- weight transpose+convert tile: W[K][N] f32 -> Wt[N][K] bf16
__device__ __forceinline__ void wtrans_tile(const float* __restrict__ W, bf16_t* __restrict__ Wt,
                                            int K, int N, int bk, int bn, int tid,
                                            float* tile /* 64*65 f32 */) {
  #pragma unroll
  for (int i = 0; i < 4; ++i) {
    int c = i * 256 + tid;             // 0..1023
    int r = c >> 4, q = c & 15;
    f32x4 v = *(const f32x4*)(W + (size_t)(bk * 64 + r) * N + bn * 64 + q * 4);
    tile[r * 65 + q * 4 + 0] = v[0]; tile[r * 65 + q * 4 + 1] = v[1];
    tile[r * 65 + q * 4 + 2] = v[2]; tile[r * 65 + q * 4 + 3] = v[3];
  }
  __syncthreads();
  #pragma unroll
  for (int i = 0; i < 2; ++i) {
    int c = i * 256 + tid;             // 0..511
    int n = c >> 3, kc = c & 7;
    bf16x8 o;
    #pragma unroll
    for (int j = 0; j < 8; ++j) o[j] = (bf16_t)tile[(kc * 8 + j) * 65 + n];
    *(bf16x8*)(Wt + (size_t)(bn * 64 + n) * K + bk * 64 + kc * 8) = o;
  }
}

// ---------------- ada_plus: ada GEMV + wq/wk/wv transposes + bcat + vt pad
// (riders don't need emb -> they overlap the ada GEMV instead of serializing)
// roles: [0,480) ada | [480,2080) wq | [2080,3680) wk | [3680,5280) wv
//        [5280,5310) bcat | [5310,5598) vt pad (row 40 = ONES, 41..47 zero)
__global__ __launch_bounds__(256) void ada_plus(
    const float* __restrict__ te, const float* __restrict__ aw,
    const float* __restrict__ ab, float* __restrict__ emb,
    const float* __restrict__ wq, const float* __restrict__ wk, const float* __restrict__ wv,
    bf16_t* __restrict__ wqkvT,
    const float* __restrict__ bq, const float* __restrict__ bk, const float* __restrict__ bv,
    float* __restrict__ bqkv, bf16_t* __restrict__ vt) {
  __shared__ float tile[64 * 65];
  const int b = blockIdx.x, t = threadIdx.x;
  if (b < 480) {
    // parallel ada: 64 j x 4 k-chunks of 128
    float* red = tile;                 // reuse smem
    const int j = b * 64 + (t & 63);
    const int kc = t >> 6;
    const float* awp = aw + (size_t)(kc * 128) * (12 * D) + j;
    const float* tep = te + kc * 128;
    float a0 = 0.f, a1 = 0.f, a2 = 0.f, a3 = 0.f;
    #pragma unroll 8
    for (int k = 0; k < 128; k += 4) {
      a0 = fmaf(tep[k],     awp[(size_t)k * (12 * D)],       a0);
      a1 = fmaf(tep[k + 1], awp[(size_t)(k + 1) * (12 * D)], a1);
      a2 = fmaf(tep[k + 2], awp[(size_t)(k + 2) * (12 * D)], a2);
      a3 = fmaf(tep[k + 3], awp[(size_t)(k + 3) * (12 * D)], a3);
    }
    red[kc * 64 + (t & 63)] = (a0 + a1) + (a2 + a3);
    __syncthreads();
    if (t < 64)
      emb[j] = ab[j] + red[t] + red[64 + t] + red[128 + t] + red[192 + t];
  } else if (b < 2080) {
    int l = b - 480;  wtrans_tile(wq, wqkvT,                     D, D, l % 40, l / 40, t, tile);
  } else if (b < 3680) {
    int l = b - 2080; wtrans_tile(wk, wqkvT + (size_t)D * D,     D, D, l % 40, l / 40, t, tile);
  } else if (b < 5280) {
    int l = b - 3680; wtrans_tile(wv, wqkvT + (size_t)2 * D * D, D, D, l % 40, l / 40, t, tile);
  } else if (b < 5310) {
    int i = (b - 5280) * 256 + t;
    bqkv[i] = i < D ? bq[i] : (i < 2 * D ? bk[i - D] : bv[i - 2 * D]);
  } else {
    int i = (b - 5310) * 256 + t;      // 73728 granules = 64 heads * 1152, rows 40..47
    int h = i / 1152, g = i - h * 1152;
    bf16x8 z = {};
    if (g < 144) {                     // offsets [0,1152) = row 40 -> ones
      #pragma unroll
      for (int j = 0; j < 8; ++j) z[j] = (bf16_t)1.f;
    }
    *(bf16x8*)(vt + ((size_t)h * 48 + 40) * SEQ + g * 8) = z;
  }
}

// ---------------- LN + adaLN modulation -> bf16 x  (rows 0..127 = encoder)
__global__ void ln_mod(const float* __restrict__ hid, const float* __restrict__ enc,
                       const float* __restrict__ emb, bf16_t* __restrict__ out,
                       int shift_h, int scale_h, int shift_e, int scale_e) {
  int row = blockIdx.x, tid = threadIdx.x;
  const float *src, *sc, *sh;
  if (row < TENC) { src = enc + (size_t)row * D;          sc = emb + scale_e * D; sh = emb + shift_e * D; }
  else            { src = hid + (size_t)(row - TENC) * D; sc = emb + scale_h * D; sh = emb + shift_h * D; }
  float v[10], s = 0.f, s2 = 0.f;
  #pragma unroll
  for (int i = 0; i < 10; ++i) { v[i] = src[tid + i * 256]; s += v[i]; s2 += v[i] * v[i]; }
  #pragma unroll
  for (int o = 32; o > 0; o >>= 1) { s += __shfl_down(s, o); s2 += __shfl_down(s2, o); }
  __shared__ float red[8];
  int wv = tid >> 6, ln = tid & 63;
  if (ln == 0) { red[wv] = s; red[4 + wv] = s2; }
  __syncthreads();
  s  = red[0] + red[1] + red[2] + red[3];
  s2 = red[4] + red[5] + red[6] + red[7];
  float mean = s * (1.f / D);
  float rstd = rsqrtf(s2 * (1.f / D) - mean * mean + 1e-5f);
  #pragma unroll
  for (int i = 0; i < 10; ++i) {
    int c = tid + i * 256;
    out[(size_t)row * D + c] = (bf16_t)((v[i] - mean) * rstd * (1.f + sc[c]) + sh[c]);
  }
}

// ---------------- GEMM body (m97 structure): C[1152][N] = A_bf16 @ Bt_bf16^T
// EPI 1: gelu->bf16   EPI 4: f32 partial (no bias)
template<int EPI>
__device__ __forceinline__ void gemm_body(
    bf16_t* As, bf16_t* Bs,
    const bf16_t* __restrict__ A, const bf16_t* __restrict__ Bt,
    const float* __restrict__ bias, int Kld, int ksteps, int N, int nM, int nMN,
    int nwg, int orig,
    bf16_t* __restrict__ outb, float* __restrict__ outp) {
  const int q8 = nwg >> 3, r8 = nwg & 7;
  const int xcd = orig & 7, pos = orig >> 3;
  const int wg = (xcd < r8 ? xcd * (q8 + 1) : r8 * (q8 + 1) + (xcd - r8) * q8) + pos;
  const int part = wg / nMN, rest = wg - part * nMN;
  const int bm = rest % nM, bn = rest / nM;
  const int m0 = bm * 128, n0 = bn * 128;
  const int kbase = part * ksteps;
  const int tid = threadIdx.x, wv = tid >> 6, ln = tid & 63;
  const int wr = wv >> 1, wc = wv & 1, lr = ln & 15, lg = ln >> 4;

  f32x4 acc[4][4];
  const f32x4 zero = {0.f, 0.f, 0.f, 0.f};
  #pragma unroll
  for (int m = 0; m < 4; ++m)
    #pragma unroll
    for (int n = 0; n < 4; ++n) acc[m][n] = zero;

  for (int t = 0; t < ksteps; ++t) {
    const int k0 = (kbase + t) << 6;
    __syncthreads();
    #pragma unroll
    for (int i = 0; i < 4; ++i) {        // A: 128x64 = 16 chunks
      int g = wv * 4 + i;
      int s = g * 64 + ln;
      int r = s >> 3, ks = s & 7;
      gld_lds16(A + (size_t)(m0 + r) * Kld + k0 + ((ks ^ (r & 7)) << 3), &As[g * 512]);
    }
    #pragma unroll
    for (int i = 0; i < 4; ++i) {        // Bt: 128x64 = 16 chunks
      int g = wv * 4 + i;
      int s = g * 64 + ln;
      int r = s >> 3, ks = s & 7;
      gld_lds16(Bt + (size_t)(n0 + r) * Kld + k0 + ((ks ^ (r & 7)) << 3), &Bs[g * 512]);
    }
    __syncthreads();
    #pragma unroll
    for (int ks2 = 0; ks2 < 2; ++ks2) {
      int ko = ks2 * 4 + lg;
      bf16x8 af[4], bfr[4];
      #pragma unroll
      for (int m = 0; m < 4; ++m) {
        int r = wr * 64 + m * 16 + lr;
        af[m] = *(const bf16x8*)&As[r * 64 + ((ko ^ (r & 7)) << 3)];
      }
      #pragma unroll
      for (int n = 0; n < 4; ++n) {
        int c = wc * 64 + n * 16 + lr;
        bfr[n] = *(const bf16x8*)&Bs[c * 64 + ((ko ^ (c & 7)) << 3)];
      }
      #pragma unroll
      for (int m = 0; m < 4; ++m)
        #pragma unroll
        for (int n = 0; n < 4; ++n)
          acc[m][n] = __builtin_amdgcn_mfma_f32_16x16x32_bf16(af[m], bfr[n], acc[m][n], 0, 0, 0);
    }
  }

  #pragma unroll
  for (int m = 0; m < 4; ++m) {
    int row = m0 + wr * 64 + m * 16 + (lg << 2);
    #pragma unroll
    for (int n = 0; n < 4; ++n) {
      int col = n0 + wc * 64 + n * 16 + lr;
      float bv = (EPI == 4) ? 0.f : bias[col];
      #pragma unroll
      for (int r = 0; r < 4; ++r) {
        float val = acc[m][n][r] + bv;
        int rr = row + r;
        if (EPI == 1) {
          float z = 0.7978845608028654f * (val + 0.044715f * val * val * val);
          float t2 = 1.f - 2.f / (__expf(2.f * z) + 1.f);
          outb[(size_t)rr * N + col] = (bf16_t)(0.5f * val * (1.f + t2));
        } else {
          outp[(size_t)part * SEQ * N + (size_t)rr * N + col] = val;
        }
      }
    }
  }
}

template<int EPI>
__global__ __launch_bounds__(256, 4) void gemm4(
    const bf16_t* __restrict__ A, const bf16_t* __restrict__ Bt,
    const float* __restrict__ bias, int Kld, int ksteps, int N, int nM, int nMN,
    bf16_t* __restrict__ outb, float* __restrict__ outp) {
  __shared__ bf16_t As[128 * 64];
  __shared__ bf16_t Bs[128 * 64];
  gemm_body<EPI>(As, Bs, A, Bt, bias, Kld, ksteps, N, nM, nMN, gridDim.x, blockIdx.x,
                 outb, outp);
}

// ---------------- QKV GEMM (split-K x2, partials) + woT transpose riding
// roles: [0,1080) gemm | [1080,2680) woT (40x40 tiles)
// NOTE: qparts spans w1T + first 18.4MB of w2T -> w2T must NOT be written here.
__global__ __launch_bounds__(256, 4) void qkv_g(
    const bf16_t* __restrict__ A, const bf16_t* __restrict__ wqkvT,
    float* __restrict__ qparts,
    const float* __restrict__ wo, bf16_t* __restrict__ woT) {
  __shared__ char smem[32768] __attribute__((aligned(16)));
  const int b = blockIdx.x;
  if (b < 1080) {
    gemm_body<4>((bf16_t*)smem, (bf16_t*)(smem + 16384), A, wqkvT, nullptr,
                 D, 20, 3 * D, 9, 540, 1080, b, nullptr, qparts);
  } else {
    int l = b - 1080;
    wtrans_tile(wo, woT, D, D, l % 40, l / 40, threadIdx.x, (float*)smem);
  }
}

// ---------------- O-proj GEMM (split-K x2) + w2T transpose riding
// roles: [0,360) gemm | [360,6760) w2T (160x40 tiles)
__global__ __launch_bounds__(256, 4) void oproj_plus(
    const bf16_t* __restrict__ A, const bf16_t* __restrict__ woT,
    float* __restrict__ oparts,
    const float* __restrict__ w2, bf16_t* __restrict__ w2T) {
  __shared__ char smem[32768] __attribute__((aligned(16)));
  const int b = blockIdx.x;
  if (b < 360) {
    gemm_body<4>((bf16_t*)smem, (bf16_t*)(smem + 16384), A, woT, nullptr,
                 D, 20, D, 9, 180, 360, b, nullptr, oparts);
  } else {
    int l = b - 360;
    wtrans_tile(w2, w2T, FFD, D, l % 160, l / 160, threadIdx.x, (float*)smem);
  }
}

// ---------------- qkv_red: sum partials + bias + per-head LN + RoPE -> qbb/kbb bf16, V -> vt
__global__ __launch_bounds__(256) void qkv_red(
    const float* __restrict__ parts, const float* __restrict__ bqkv,
    const float* __restrict__ rc, const float* __restrict__ rs,
    bf16_t* __restrict__ qb, bf16_t* __restrict__ kb, bf16_t* __restrict__ vt) {
  const int r = blockIdx.x, t = threadIdx.x;
  const int h = t >> 2, sub = t & 3;
  __shared__ float cs_s[HD], sn_s[HD];
  const bool rope = (r >= TENC);
  if (rope && t < 2 * HD) {
    if (t < HD) cs_s[t] = rc[(size_t)(r - TENC) * HD + t];
    else        sn_s[t - HD] = rs[(size_t)(r - TENC) * HD + (t - HD)];
  }
  const float* p0 = parts + (size_t)r * (3 * D);
  const float* p1 = p0 + (size_t)SEQ * (3 * D);
  const int cq = h * HD + sub * 10;
  float q[10], k[10], v[10];
  #pragma unroll
  for (int j = 0; j < 10; ++j) {
    q[j] = p0[cq + j] + p1[cq + j] + bqkv[cq + j];
    k[j] = p0[D + cq + j] + p1[D + cq + j] + bqkv[D + cq + j];
    v[j] = p0[2 * D + cq + j] + p1[2 * D + cq + j] + bqkv[2 * D + cq + j];
  }
  __syncthreads();
  float qs = 0.f, qs2 = 0.f, ks = 0.f, ks2 = 0.f;
  #pragma unroll
  for (int j = 0; j < 10; ++j) { qs += q[j]; qs2 += q[j] * q[j]; ks += k[j]; ks2 += k[j] * k[j]; }
  qs += __shfl_xor(qs, 1); qs += __shfl_xor(qs, 2);
  qs2 += __shfl_xor(qs2, 1); qs2 += __shfl_xor(qs2, 2);
  ks += __shfl_xor(ks, 1); ks += __shfl_xor(ks, 2);
  ks2 += __shfl_xor(ks2, 1); ks2 += __shfl_xor(ks2, 2);
  float qm = qs * (1.f / HD), km = ks * (1.f / HD);
  float qr = rsqrtf(qs2 * (1.f / HD) - qm * qm + 1e-5f);
  float kr = rsqrtf(ks2 * (1.f / HD) - km * km + 1e-5f);
  #pragma unroll
  for (int j = 0; j < 10; ++j) { q[j] = (q[j] - qm) * qr; k[j] = (k[j] - km) * kr; }
  if (rope) {
    float pq[10], pk[10];
    #pragma unroll
    for (int j = 0; j < 10; ++j) { pq[j] = __shfl_xor(q[j], 2); pk[j] = __shfl_xor(k[j], 2); }
    #pragma unroll
    for (int j = 0; j < 10; ++j) {
      int d = sub * 10 + j;
      float c = cs_s[d], s = sn_s[d];
      if (d < 20) { q[j] = q[j] * c - pq[j] * s; k[j] = k[j] * c - pk[j] * s; }
      else        { q[j] = q[j] * c + pq[j] * s; k[j] = k[j] * c + pk[j] * s; }
    }
  }
  bf16_t* qd = qb + ((size_t)h * SEQ + r) * 64;
  bf16_t* kd = kb + ((size_t)h * SEQ + r) * 64;
  const float qscale = 0.15811388300841897f;  // 1/sqrt(40)
  #pragma unroll
  for (int j = 0; j < 10; ++j) {
    int d = sub * 10 + j;
    qd[d] = (bf16_t)(q[j] * qscale);
    kd[d] = (bf16_t)k[j];
  }
  #pragma unroll
  for (int j = 0; j < 6; ++j) {
    int d = 40 + sub * 6 + j;
    qd[d] = (bf16_t)0.f; kd[d] = (bf16_t)0.f;
  }
  #pragma unroll
  for (int j = 0; j < 10; ++j) {
    int d = sub * 10 + j;
    vt[((size_t)h * 48 + d) * SEQ + r] = (bf16_t)v[j];
  }
}

// ---------------- split-K reduce + bias + gate + residual -> f32 out (final)
template<int P>
__global__ void redk(const float* __restrict__ parts, const float* __restrict__ bias,
                     const float* __restrict__ emb, int gate_h, int gate_e,
                     const float* __restrict__ res_h, const float* __restrict__ res_e,
                     float* __restrict__ out_h, float* __restrict__ out_e) {
  int idx = blockIdx.x * 256 + threadIdx.x;      // over SEQ*D/4
  int row = idx / (D / 4), col = (idx - row * (D / 4)) * 4;
  f32x4 s = *(const f32x4*)(bias + col);
  #pragma unroll
  for (int p = 0; p < P; ++p)
    s += *(const f32x4*)(parts + (size_t)p * SEQ * D + (size_t)row * D + col);
  const float* res; float* out; int g;
  int r2;
  if (row < TENC) { res = res_e; out = out_e; g = gate_e; r2 = row; }
  else            { res = res_h; out = out_h; g = gate_h; r2 = row - TENC; }
  f32x4 g4 = *(const f32x4*)(emb + (size_t)g * D + col);
  f32x4 rr4 = *(const f32x4*)(res + (size_t)r2 * D + col);
  f32x4 o;
  #pragma unroll
  for (int j = 0; j < 4; ++j) o[j] = rr4[j] + s[j] * g4[j];
  *(f32x4*)(out + (size_t)r2 * D + col) = o;
}

// ---------------- split-K reduce + gate + residual -> h1/e1 f32, THEN LN+mod -> xln bf16
template<int P>
__global__ __launch_bounds__(256) void redk_ln(
    const float* __restrict__ parts, const float* __restrict__ bias,
    const float* __restrict__ emb, int gate_h, int gate_e,
    int shift_h, int scale_h, int shift_e, int scale_e,
    const float* __restrict__ res_h, const float* __restrict__ res_e,
    float* __restrict__ out_h, float* __restrict__ out_e, bf16_t* __restrict__ xout) {
  int row = blockIdx.x, tid = threadIdx.x;
  const float* res; float* out; int g, sh, sc; int r2;
  if (row < TENC) { res = res_e; out = out_e; g = gate_e; sh = shift_e; sc = scale_e; r2 = row; }
  else            { res = res_h; out = out_h; g = gate_h; sh = shift_h; sc = scale_h; r2 = row - TENC; }
  float v[10], s = 0.f, s2 = 0.f;
  #pragma unroll
  for (int i = 0; i < 10; ++i) {
    int c = tid + i * 256;
    float val = bias[c];
    #pragma unroll
    for (int p = 0; p < P; ++p) val += parts[(size_t)p * SEQ * D + (size_t)row * D + c];
    val = res[(size_t)r2 * D + c] + val * emb[(size_t)g * D + c];
    out[(size_t)r2 * D + c] = val;
    v[i] = val; s += val; s2 += val * val;
  }
  #pragma unroll
  for (int o = 32; o > 0; o >>= 1) { s += __shfl_down(s, o); s2 += __shfl_down(s2, o); }
  __shared__ float red[8];
  int wvv = tid >> 6, lnn = tid & 63;
  if (lnn == 0) { red[wvv] = s; red[4 + wvv] = s2; }
  __syncthreads();
  s  = red[0] + red[1] + red[2] + red[3];
  s2 = red[4] + red[5] + red[6] + red[7];
  float mean = s * (1.f / D);
  float rstd = rsqrtf(s2 * (1.f / D) - mean * mean + 1e-5f);
  #pragma unroll
  for (int i = 0; i < 10; ++i) {
    int c = tid + i * 256;
    xout[(size_t)row * D + c] =
        (bf16_t)((v[i] - mean) * rstd * (1.f + emb[(size_t)sc * D + c]) + emb[(size_t)sh * D + c]);
  }
}

// ---------------- attention (fixed-max softmax, MFMA denominator, 3 q-frags/wave)
// block = 192 q-rows x 1 head; 4 waves x 48 q-rows (3 fragments of 16).
// roles: [0,384) attn | [384,6784) w1T
__global__ __launch_bounds__(256) void attn_plus(
    const bf16_t* __restrict__ qb, const bf16_t* __restrict__ kb,
    const bf16_t* __restrict__ vt, bf16_t* __restrict__ obf,
    const float* __restrict__ w1, bf16_t* __restrict__ w1T) {
  __shared__ char smem[38912] __attribute__((aligned(16)));
  const int b = blockIdx.x;
  if (b >= 384) {
    int l = b - 384;
    wtrans_tile(w1, w1T, D, FFD, l % 40, l / 40, threadIdx.x, (float*)smem);
    return;
  }
  bf16_t* Ks = (bf16_t*)smem;                 // [64*64]  8 KB
  bf16_t* Vs = (bf16_t*)(smem + 8192);        // [48*64]  6 KB
  bf16_t* Ps = (bf16_t*)(smem + 14336);       // [12][16*64] 24 KB (wave*3+qf)
  const int h = b & 63;
  const int qblk = b >> 6;                    // 6 q-blocks of 192
  const int tid = threadIdx.x, wv = tid >> 6, ln = tid & 63;
  const int qbase = qblk * 192 + wv * 48;
  const int lr = ln & 15, lg = ln >> 4;

  bf16x8 af[3][2];
  #pragma unroll
  for (int qf = 0; qf < 3; ++qf) {
    const bf16_t* qp = qb + ((size_t)h * SEQ + qbase + qf * 16 + lr) * 64 + lg * 8;
    af[qf][0] = *(const bf16x8*)(qp);
    af[qf][1] = *(const bf16x8*)(qp + 32);
  }
  const f32x4 zero = {0.f, 0.f, 0.f, 0.f};
  f32x4 acc[3][3];
  #pragma unroll
  for (int qf = 0; qf < 3; ++qf) { acc[qf][0] = zero; acc[qf][1] = zero; acc[qf][2] = zero; }

  const bf16_t* kbh = kb + (size_t)h * SEQ * 64;
  const bf16_t* vth = vt + (size_t)h * 48 * SEQ;

  for (int kv0 = 0; kv0 < SEQ; kv0 += 64) {
    __syncthreads();
    #pragma unroll
    for (int i = 0; i < 2; ++i) {
      int g = wv * 2 + i;
      int slot = g * 64 + ln;
      int kr = slot >> 3, so = slot & 7;
      gld_lds16(kbh + (size_t)(kv0 + kr) * 64 + ((so ^ (kr & 7)) << 3), &Ks[g * 512]);
    }
    #pragma unroll
    for (int i = 0; i < 2; ++i) {
      int g = wv + 4 * i;
      if (g < 6) {
        int slot = g * 64 + ln;
        int dr = slot >> 3, so = slot & 7;
        gld_lds16(vth + (size_t)dr * SEQ + kv0 + ((so ^ (dr & 7)) << 3), &Vs[g * 512]);
      }
    }
    __syncthreads();
    #pragma unroll
    for (int nt = 0; nt < 4; ++nt) {
      int kvr = nt * 16 + lr;
      bf16x8 bk0 = *(const bf16x8*)&Ks[kvr * 64 + ((lg ^ (kvr & 7)) << 3)];
      bf16x8 bk1 = *(const bf16x8*)&Ks[kvr * 64 + (((4 + lg) ^ (kvr & 7)) << 3)];
      #pragma unroll
      for (int qf = 0; qf < 3; ++qf) {
        f32x4 s = zero;
        s = __builtin_amdgcn_mfma_f32_16x16x32_bf16(af[qf][0], bk0, s, 0, 0, 0);
        s = __builtin_amdgcn_mfma_f32_16x16x32_bf16(af[qf][1], bk1, s, 0, 0, 0);
        #pragma unroll
        for (int r = 0; r < 4; ++r) {
          float p = exp2f(fmaf(s[r], 1.44269504f, -9.377517766f));
          int q = lg * 4 + r;
          int kv = nt * 16 + lr;
          Ps[(wv * 3 + qf) * 1024 + q * 64 + ((((kv >> 3) ^ (q & 7)) << 3) | (kv & 7))] = (bf16_t)p;
        }
      }
    }
    bf16x8 pa[3][2];
    #pragma unroll
    for (int qf = 0; qf < 3; ++qf)
      #pragma unroll
      for (int kk = 0; kk < 2; ++kk)
        pa[qf][kk] = *(const bf16x8*)&Ps[(wv * 3 + qf) * 1024 + lr * 64 + (((kk * 4 + lg) ^ (lr & 7)) << 3)];
    #pragma unroll
    for (int dt = 0; dt < 3; ++dt) {
      int dr = dt * 16 + lr;
      #pragma unroll
      for (int kk = 0; kk < 2; ++kk) {
        bf16x8 bv = *(const bf16x8*)&Vs[dr * 64 + (((kk * 4 + lg) ^ (dr & 7)) << 3)];
        acc[0][dt] = __builtin_amdgcn_mfma_f32_16x16x32_bf16(pa[0][kk], bv, acc[0][dt], 0, 0, 0);
        acc[1][dt] = __builtin_amdgcn_mfma_f32_16x16x32_bf16(pa[1][kk], bv, acc[1][dt], 0, 0, 0);
        acc[2][dt] = __builtin_amdgcn_mfma_f32_16x16x32_bf16(pa[2][kk], bv, acc[2][dt], 0, 0, 0);
      }
    }
  }
  #pragma unroll
  for (int qf = 0; qf < 3; ++qf) {
    float linv[4];
    #pragma unroll
    for (int r = 0; r < 4; ++r)
      linv[r] = 1.f / __shfl(acc[qf][2][r], (ln & 48) | 8);
    #pragma unroll
    for (int dt = 0; dt < 3; ++dt) {
      int d = dt * 16 + lr;
      if (d < HD) {
        #pragma unroll
        for (int r = 0; r < 4; ++r) {
          int q = qbase + qf * 16 + lg * 4 + r;
          obf[(size_t)q * D + h * HD + d] = (bf16_t)(acc[qf][dt][r] * linv[r]);
        }
      }
    }
  }
}

extern "C" void kernel_launch(void* const* d_in, const int* in_sizes, int n_in,
                              void* d_out, int out_size, void* d_ws, size_t ws_size,
                              hipStream_t stream) {
  const float* hid = (const float*)d_in[0];
  const float* enc = (const float*)d_in[1];
  const float* tem = (const float*)d_in[2];
  const float* rc  = (const float*)d_in[3];
  const float* rs  = (const float*)d_in[4];
  const float* aw  = (const float*)d_in[5];
  const float* ab  = (const float*)d_in[6];
  const float* wq  = (const float*)d_in[7];
  const float* bq  = (const float*)d_in[8];
  const float* wk  = (const float*)d_in[9];
  const float* bk  = (const float*)d_in[10];
  const float* wvv = (const float*)d_in[11];
  const float* bv  = (const float*)d_in[12];
  const float* wo  = (const float*)d_in[13];
  const float* bo  = (const float*)d_in[14];
  const float* w1  = (const float*)d_in[15];
  const float* b1  = (const float*)d_in[16];
  const float* w2  = (const float*)d_in[17];
  const float* b2  = (const float*)d_in[18];
  float* out_hid = (float*)d_out;
  float* out_enc = out_hid + (size_t)THID * D;

  char* ws = (char*)d_ws;
  size_t off = 0;
  auto alloc = [&](size_t b) { char* p = ws + off; off += (b + 255) & ~(size_t)255; return p; };
  float*  emb  = (float*) alloc((size_t)12 * D * 4);
  bf16_t* xln  = (bf16_t*)alloc((size_t)SEQ * D * 2);          // also attn-out bf16
  bf16_t* aff  = (bf16_t*)alloc((size_t)SEQ * FFD * 2);        // FF1 activation 23.6 MB
  bf16_t* vt   = (bf16_t*)alloc((size_t)NH * 48 * SEQ * 2);    // V^T bf16, d padded to 48 (row40=ones)
  bf16_t* qbb  = (bf16_t*)alloc((size_t)NH * SEQ * 64 * 2);    // Q bf16 padded; +kbb = h1/e1 after attn
  bf16_t* kbb  = (bf16_t*)alloc((size_t)NH * SEQ * 64 * 2);
  bf16_t* wqkvT= (bf16_t*)alloc((size_t)3 * D * D * 2);        // [7680][2560] 39.3 MB
  bf16_t* woT  = (bf16_t*)alloc((size_t)D * D * 2);            // 13.1 MB, after wqkvT
  bf16_t* w1T  = (bf16_t*)alloc((size_t)FFD * D * 2);          // 52.4 MB
  bf16_t* w2T  = (bf16_t*)alloc((size_t)D * FFD * 2);          // 52.4 MB
  float*  bqkv = (float*) alloc((size_t)3 * D * 4);
  bf16_t* obf = xln;
  float*  h1  = (float*)qbb;          // residual-1 hid (qbb/kbb dead after attn)
  float*  e1  = h1 + (size_t)THID * D;
  float*  qparts = (float*)w1T;       // QKV partials 70.8MB = w1T + first 18.4MB of w2T.
                                      //   Dead after L4; w1T/w2T written in L5/L6 (after).
  float*  oparts = (float*)wqkvT;     // O-proj partials 2x11.8MB, fits INSIDE wqkvT
  float*  fparts = (float*)wqkvT;     // FF2 partials 8x11.8=94.4MB: spans wqkvT+woT+42MB of
                                      //   w1T. woT dead after L6-read... read L6, FF2 is L9 (dead);
                                      //   w1T dead after L8 (FF1); does NOT reach w2T (94.4<104.8). OK.

  // L1: ada GEMV (480) + wq/wk/wv transposes (4800) + bcat (30) + vt pad (288)
  ada_plus<<<dim3(5598), dim3(256), 0, stream>>>(tem, aw, ab, emb,
      wq, wk, wvv, wqkvT, bq, bk, bv, bqkv, vt);
  // L2: LN+mod #1
  ln_mod<<<dim3(SEQ), dim3(256), 0, stream>>>(hid, enc, emb, xln, 0, 2, 1, 3);
  // L3: QKV GEMM split-K x2 (1080) + woT (1600) rider  [NO w2T here: qparts race]
  qkv_g<<<dim3(2680), dim3(256), 0, stream>>>(xln, wqkvT, qparts, wo, woT);
  // L4: QKV reduce + LN + RoPE + pack  (qparts dies here)
  qkv_red<<<dim3(SEQ), dim3(256), 0, stream>>>(qparts, bqkv, rc, rs, qbb, kbb, vt);
  // L5: attention (384, 3 q-frags/wave) + w1T (6400) rider
  attn_plus<<<dim3(6784), dim3(256), 0, stream>>>(qbb, kbb, vt, obf, w1, w1T);
  // L6: O-proj split-K x2 (360) + w2T (6400) rider
  oproj_plus<<<dim3(6760), dim3(256), 0, stream>>>(obf, woT, oparts, w2, w2T);
  // L7: reduce + gate + residual -> h1/e1, fused LN+mod #2 -> xln
  redk_ln<2><<<dim3(SEQ), dim3(256), 0, stream>>>(oparts, bo, emb, 4, 5, 6, 8, 7, 9,
      hid, enc, h1, e1, xln);
  // L8: FF1
  gemm4<1><<<dim3(720), dim3(256), 0, stream>>>(xln, w1T, b1, D, 40, FFD, 9, 720,
      aff, nullptr);
  // L9: FF2 split-K x8 -> partials (grid 1440 = 5.6/CU, saturates 4-block/CU capacity)
  gemm4<4><<<dim3(1440), dim3(256), 0, stream>>>(aff, w2T, nullptr, FFD, 20, D, 9, 180,
      nullptr, fparts);
  // L10: final reduce + gate + residual -> d_out
  redk<8><<<dim3(2880), dim3(256), 0, stream>>>(fparts, b2, emb, 10, 11, h1, e1, out_hid, out_enc);
}

// Round 14
// 422.252 us; speedup vs baseline: 1.0301x; 1.0301x over previous
//
#include <hip/hip_runtime.h>
#include <stdint.h>

#define D 2560
#define NH 64
#define HD 40
#define TE_ 512
#define FFD 10240
#define TENC 128
#define THID 1024
#define SEQ 1152   // TENC + THID

typedef __bf16 bf16_t;
typedef __bf16 bf16x8 __attribute__((ext_vector_type(8)));
typedef float  f32x4  __attribute__((ext_vector_type(4)));

__device__ __forceinline__ void gld_lds16(const void* g, void* l) {
  __builtin_amdgcn_global_load_lds((__attribute__((address_space(1))) void*)(g),
                                   (__attribute__((address_space(3))) void*)(l), 16, 0, 0);
}

// ---------------- weight transpose+convert tile: W[K][N] f32 -> Wt[N][K] bf16
__device__ __forceinline__ void wtrans_tile(const float* __restrict__ W, bf16_t* __restrict__ Wt,
                                            int K, int N, int bk, int bn, int tid,
                                            float* tile /* 64*65 f32 */) {
  #pragma unroll
  for (int i = 0; i < 4; ++i) {
    int c = i * 256 + tid;             // 0..1023
    int r = c >> 4, q = c & 15;
    f32x4 v = *(const f32x4*)(W + (size_t)(bk * 64 + r) * N + bn * 64 + q * 4);
    tile[r * 65 + q * 4 + 0] = v[0]; tile[r * 65 + q * 4 + 1] = v[1];
    tile[r * 65 + q * 4 + 2] = v[2]; tile[r * 65 + q * 4 + 3] = v[3];
  }
  __syncthreads();
  #pragma unroll
  for (int i = 0; i < 2; ++i) {
    int c = i * 256 + tid;             // 0..511
    int n = c >> 3, kc = c & 7;
    bf16x8 o;
    #pragma unroll
    for (int j = 0; j < 8; ++j) o[j] = (bf16_t)tile[(kc * 8 + j) * 65 + n];
    *(bf16x8*)(Wt + (size_t)(bn * 64 + n) * K + bk * 64 + kc * 8) = o;
  }
}

// ---------------- ada_plus: ada GEMV + wq/wk/wv transposes + bcat + vt pad
// roles: [0,480) ada | [480,2080) wq | [2080,3680) wk | [3680,5280) wv
//        [5280,5310) bcat | [5310,5598) vt pad (row 40 = ONES, 41..47 zero)
__global__ __launch_bounds__(256) void ada_plus(
    const float* __restrict__ te, const float* __restrict__ aw,
    const float* __restrict__ ab, float* __restrict__ emb,
    const float* __restrict__ wq, const float* __restrict__ wk, const float* __restrict__ wv,
    bf16_t* __restrict__ wqkvT,
    const float* __restrict__ bq, const float* __restrict__ bk, const float* __restrict__ bv,
    float* __restrict__ bqkv, bf16_t* __restrict__ vt) {
  __shared__ float tile[64 * 65];
  const int b = blockIdx.x, t = threadIdx.x;
  if (b < 480) {
    float* red = tile;
    const int j = b * 64 + (t & 63);
    const int kc = t >> 6;
    const float* awp = aw + (size_t)(kc * 128) * (12 * D) + j;
    const float* tep = te + kc * 128;
    float a0 = 0.f, a1 = 0.f, a2 = 0.f, a3 = 0.f;
    #pragma unroll 8
    for (int k = 0; k < 128; k += 4) {
      a0 = fmaf(tep[k],     awp[(size_t)k * (12 * D)],       a0);
      a1 = fmaf(tep[k + 1], awp[(size_t)(k + 1) * (12 * D)], a1);
      a2 = fmaf(tep[k + 2], awp[(size_t)(k + 2) * (12 * D)], a2);
      a3 = fmaf(tep[k + 3], awp[(size_t)(k + 3) * (12 * D)], a3);
    }
    red[kc * 64 + (t & 63)] = (a0 + a1) + (a2 + a3);
    __syncthreads();
    if (t < 64)
      emb[j] = ab[j] + red[t] + red[64 + t] + red[128 + t] + red[192 + t];
  } else if (b < 2080) {
    int l = b - 480;  wtrans_tile(wq, wqkvT,                     D, D, l % 40, l / 40, t, tile);
  } else if (b < 3680) {
    int l = b - 2080; wtrans_tile(wk, wqkvT + (size_t)D * D,     D, D, l % 40, l / 40, t, tile);
  } else if (b < 5280) {
    int l = b - 3680; wtrans_tile(wv, wqkvT + (size_t)2 * D * D, D, D, l % 40, l / 40, t, tile);
  } else if (b < 5310) {
    int i = (b - 5280) * 256 + t;
    bqkv[i] = i < D ? bq[i] : (i < 2 * D ? bk[i - D] : bv[i - 2 * D]);
  } else {
    int i = (b - 5310) * 256 + t;      // 73728 granules = 64 heads * 1152, rows 40..47
    int h = i / 1152, g = i - h * 1152;
    bf16x8 z = {};
    if (g < 144) {                     // offsets [0,1152) = row 40 -> ones
      #pragma unroll
      for (int j = 0; j < 8; ++j) z[j] = (bf16_t)1.f;
    }
    *(bf16x8*)(vt + ((size_t)h * 48 + 40) * SEQ + g * 8) = z;
  }
}

// ---------------- LN + adaLN modulation -> bf16 x  (rows 0..127 = encoder)
__global__ void ln_mod(const float* __restrict__ hid, const float* __restrict__ enc,
                       const float* __restrict__ emb, bf16_t* __restrict__ out,
                       int shift_h, int scale_h, int shift_e, int scale_e) {
  int row = blockIdx.x, tid = threadIdx.x;
  const float *src, *sc, *sh;
  if (row < TENC) { src = enc + (size_t)row * D;          sc = emb + scale_e * D; sh = emb + shift_e * D; }
  else            { src = hid + (size_t)(row - TENC) * D; sc = emb + scale_h * D; sh = emb + shift_h * D; }
  float v[10], s = 0.f, s2 = 0.f;
  #pragma unroll
  for (int i = 0; i < 10; ++i) { v[i] = src[tid + i * 256]; s += v[i]; s2 += v[i] * v[i]; }
  #pragma unroll
  for (int o = 32; o > 0; o >>= 1) { s += __shfl_down(s, o); s2 += __shfl_down(s2, o); }
  __shared__ float red[8];
  int wv = tid >> 6, ln = tid & 63;
  if (ln == 0) { red[wv] = s; red[4 + wv] = s2; }
  __syncthreads();
  s  = red[0] + red[1] + red[2] + red[3];
  s2 = red[4] + red[5] + red[6] + red[7];
  float mean = s * (1.f / D);
  float rstd = rsqrtf(s2 * (1.f / D) - mean * mean + 1e-5f);
  #pragma unroll
  for (int i = 0; i < 10; ++i) {
    int c = tid + i * 256;
    out[(size_t)row * D + c] = (bf16_t)((v[i] - mean) * rstd * (1.f + sc[c]) + sh[c]);
  }
}

// ---------------- GEMM body (m97 structure): C[1152][N] = A_bf16 @ Bt_bf16^T
// EPI 1: gelu->bf16   EPI 4: f32 partial (no bias)
template<int EPI>
__device__ __forceinline__ void gemm_body(
    bf16_t* As, bf16_t* Bs,
    const bf16_t* __restrict__ A, const bf16_t* __restrict__ Bt,
    const float* __restrict__ bias, int Kld, int ksteps, int N, int nM, int nMN,
    int nwg, int orig,
    bf16_t* __restrict__ outb, float* __restrict__ outp) {
  const int q8 = nwg >> 3, r8 = nwg & 7;
  const int xcd = orig & 7, pos = orig >> 3;
  const int wg = (xcd < r8 ? xcd * (q8 + 1) : r8 * (q8 + 1) + (xcd - r8) * q8) + pos;
  const int part = wg / nMN, rest = wg - part * nMN;
  const int bm = rest % nM, bn = rest / nM;
  const int m0 = bm * 128, n0 = bn * 128;
  const int kbase = part * ksteps;
  const int tid = threadIdx.x, wv = tid >> 6, ln = tid & 63;
  const int wr = wv >> 1, wc = wv & 1, lr = ln & 15, lg = ln >> 4;

  f32x4 acc[4][4];
  const f32x4 zero = {0.f, 0.f, 0.f, 0.f};
  #pragma unroll
  for (int m = 0; m < 4; ++m)
    #pragma unroll
    for (int n = 0; n < 4; ++n) acc[m][n] = zero;

  for (int t = 0; t < ksteps; ++t) {
    const int k0 = (kbase + t) << 6;
    __syncthreads();
    #pragma unroll
    for (int i = 0; i < 4; ++i) {        // A: 128x64 = 16 chunks
      int g = wv * 4 + i;
      int s = g * 64 + ln;
      int r = s >> 3, ks = s & 7;
      gld_lds16(A + (size_t)(m0 + r) * Kld + k0 + ((ks ^ (r & 7)) << 3), &As[g * 512]);
    }
    #pragma unroll
    for (int i = 0; i < 4; ++i) {        // Bt: 128x64 = 16 chunks
      int g = wv * 4 + i;
      int s = g * 64 + ln;
      int r = s >> 3, ks = s & 7;
      gld_lds16(Bt + (size_t)(n0 + r) * Kld + k0 + ((ks ^ (r & 7)) << 3), &Bs[g * 512]);
    }
    __syncthreads();
    #pragma unroll
    for (int ks2 = 0; ks2 < 2; ++ks2) {
      int ko = ks2 * 4 + lg;
      bf16x8 af[4], bfr[4];
      #pragma unroll
      for (int m = 0; m < 4; ++m) {
        int r = wr * 64 + m * 16 + lr;
        af[m] = *(const bf16x8*)&As[r * 64 + ((ko ^ (r & 7)) << 3)];
      }
      #pragma unroll
      for (int n = 0; n < 4; ++n) {
        int c = wc * 64 + n * 16 + lr;
        bfr[n] = *(const bf16x8*)&Bs[c * 64 + ((ko ^ (c & 7)) << 3)];
      }
      #pragma unroll
      for (int m = 0; m < 4; ++m)
        #pragma unroll
        for (int n = 0; n < 4; ++n)
          acc[m][n] = __builtin_amdgcn_mfma_f32_16x16x32_bf16(af[m], bfr[n], acc[m][n], 0, 0, 0);
    }
  }

  #pragma unroll
  for (int m = 0; m < 4; ++m) {
    int row = m0 + wr * 64 + m * 16 + (lg << 2);
    #pragma unroll
    for (int n = 0; n < 4; ++n) {
      int col = n0 + wc * 64 + n * 16 + lr;
      float bv = (EPI == 4) ? 0.f : bias[col];
      #pragma unroll
      for (int r = 0; r < 4; ++r) {
        float val = acc[m][n][r] + bv;
        int rr = row + r;
        if (EPI == 1) {
          float z = 0.7978845608028654f * (val + 0.044715f * val * val * val);
          float t2 = 1.f - 2.f / (__expf(2.f * z) + 1.f);
          outb[(size_t)rr * N + col] = (bf16_t)(0.5f * val * (1.f + t2));
        } else {
          outp[(size_t)part * SEQ * N + (size_t)rr * N + col] = val;
        }
      }
    }
  }
}

template<int EPI>
__global__ __launch_bounds__(256, 4) void gemm4(
    const bf16_t* __restrict__ A, const bf16_t* __restrict__ Bt,
    const float* __restrict__ bias, int Kld, int ksteps, int N, int nM, int nMN,
    bf16_t* __restrict__ outb, float* __restrict__ outp) {
  __shared__ bf16_t As[128 * 64];
  __shared__ bf16_t Bs[128 * 64];
  gemm_body<EPI>(As, Bs, A, Bt, bias, Kld, ksteps, N, nM, nMN, gridDim.x, blockIdx.x,
                 outb, outp);
}

// ---------------- QKV GEMM (split-K x2, partials) + woT transpose riding
// roles: [0,1080) gemm | [1080,2680) woT (40x40 tiles)
// NOTE: qparts spans w1T + first 18.4MB of w2T -> w2T must NOT be written here.
__global__ __launch_bounds__(256, 4) void qkv_g(
    const bf16_t* __restrict__ A, const bf16_t* __restrict__ wqkvT,
    float* __restrict__ qparts,
    const float* __restrict__ wo, bf16_t* __restrict__ woT) {
  __shared__ char smem[32768] __attribute__((aligned(16)));
  const int b = blockIdx.x;
  if (b < 1080) {
    gemm_body<4>((bf16_t*)smem, (bf16_t*)(smem + 16384), A, wqkvT, nullptr,
                 D, 20, 3 * D, 9, 540, 1080, b, nullptr, qparts);
  } else {
    int l = b - 1080;
    wtrans_tile(wo, woT, D, D, l % 40, l / 40, threadIdx.x, (float*)smem);
  }
}

// ---------------- O-proj GEMM (split-K x2) + w2T transpose riding
// roles: [0,360) gemm | [360,6760) w2T (160x40 tiles)
__global__ __launch_bounds__(256, 4) void oproj_plus(
    const bf16_t* __restrict__ A, const bf16_t* __restrict__ woT,
    float* __restrict__ oparts,
    const float* __restrict__ w2, bf16_t* __restrict__ w2T) {
  __shared__ char smem[32768] __attribute__((aligned(16)));
  const int b = blockIdx.x;
  if (b < 360) {
    gemm_body<4>((bf16_t*)smem, (bf16_t*)(smem + 16384), A, woT, nullptr,
                 D, 20, D, 9, 180, 360, b, nullptr, oparts);
  } else {
    int l = b - 360;
    wtrans_tile(w2, w2T, FFD, D, l % 160, l / 160, threadIdx.x, (float*)smem);
  }
}

// ---------------- qkv_red: sum partials + bias + per-head LN + RoPE -> qbb/kbb bf16, V -> vt
__global__ __launch_bounds__(256) void qkv_red(
    const float* __restrict__ parts, const float* __restrict__ bqkv,
    const float* __restrict__ rc, const float* __restrict__ rs,
    bf16_t* __restrict__ qb, bf16_t* __restrict__ kb, bf16_t* __restrict__ vt) {
  const int r = blockIdx.x, t = threadIdx.x;
  const int h = t >> 2, sub = t & 3;
  __shared__ float cs_s[HD], sn_s[HD];
  const bool rope = (r >= TENC);
  if (rope && t < 2 * HD) {
    if (t < HD) cs_s[t] = rc[(size_t)(r - TENC) * HD + t];
    else        sn_s[t - HD] = rs[(size_t)(r - TENC) * HD + (t - HD)];
  }
  const float* p0 = parts + (size_t)r * (3 * D);
  const float* p1 = p0 + (size_t)SEQ * (3 * D);
  const int cq = h * HD + sub * 10;
  float q[10], k[10], v[10];
  #pragma unroll
  for (int j = 0; j < 10; ++j) {
    q[j] = p0[cq + j] + p1[cq + j] + bqkv[cq + j];
    k[j] = p0[D + cq + j] + p1[D + cq + j] + bqkv[D + cq + j];
    v[j] = p0[2 * D + cq + j] + p1[2 * D + cq + j] + bqkv[2 * D + cq + j];
  }
  __syncthreads();
  float qs = 0.f, qs2 = 0.f, ks = 0.f, ks2 = 0.f;
  #pragma unroll
  for (int j = 0; j < 10; ++j) { qs += q[j]; qs2 += q[j] * q[j]; ks += k[j]; ks2 += k[j] * k[j]; }
  qs += __shfl_xor(qs, 1); qs += __shfl_xor(qs, 2);
  qs2 += __shfl_xor(qs2, 1); qs2 += __shfl_xor(qs2, 2);
  ks += __shfl_xor(ks, 1); ks += __shfl_xor(ks, 2);
  ks2 += __shfl_xor(ks2, 1); ks2 += __shfl_xor(ks2, 2);
  float qm = qs * (1.f / HD), km = ks * (1.f / HD);
  float qr = rsqrtf(qs2 * (1.f / HD) - qm * qm + 1e-5f);
  float kr = rsqrtf(ks2 * (1.f / HD) - km * km + 1e-5f);
  #pragma unroll
  for (int j = 0; j < 10; ++j) { q[j] = (q[j] - qm) * qr; k[j] = (k[j] - km) * kr; }
  if (rope) {
    float pq[10], pk[10];
    #pragma unroll
    for (int j = 0; j < 10; ++j) { pq[j] = __shfl_xor(q[j], 2); pk[j] = __shfl_xor(k[j], 2); }
    #pragma unroll
    for (int j = 0; j < 10; ++j) {
      int d = sub * 10 + j;
      float c = cs_s[d], s = sn_s[d];
      if (d < 20) { q[j] = q[j] * c - pq[j] * s; k[j] = k[j] * c - pk[j] * s; }
      else        { q[j] = q[j] * c + pq[j] * s; k[j] = k[j] * c + pk[j] * s; }
    }
  }
  bf16_t* qd = qb + ((size_t)h * SEQ + r) * 64;
  bf16_t* kd = kb + ((size_t)h * SEQ + r) * 64;
  const float qscale = 0.15811388300841897f;  // 1/sqrt(40)
  #pragma unroll
  for (int j = 0; j < 10; ++j) {
    int d = sub * 10 + j;
    qd[d] = (bf16_t)(q[j] * qscale);
    kd[d] = (bf16_t)k[j];
  }
  #pragma unroll
  for (int j = 0; j < 6; ++j) {
    int d = 40 + sub * 6 + j;
    qd[d] = (bf16_t)0.f; kd[d] = (bf16_t)0.f;
  }
  #pragma unroll
  for (int j = 0; j < 10; ++j) {
    int d = sub * 10 + j;
    vt[((size_t)h * 48 + d) * SEQ + r] = (bf16_t)v[j];
  }
}

// ---------------- split-K reduce + bias + gate + residual -> f32 out (final)
template<int P>
__global__ void redk(const float* __restrict__ parts, const float* __restrict__ bias,
                     const float* __restrict__ emb, int gate_h, int gate_e,
                     const float* __restrict__ res_h, const float* __restrict__ res_e,
                     float* __restrict__ out_h, float* __restrict__ out_e) {
  int idx = blockIdx.x * 256 + threadIdx.x;      // over SEQ*D/4
  int row = idx / (D / 4), col = (idx - row * (D / 4)) * 4;
  f32x4 s = *(const f32x4*)(bias + col);
  #pragma unroll
  for (int p = 0; p < P; ++p)
    s += *(const f32x4*)(parts + (size_t)p * SEQ * D + (size_t)row * D + col);
  const float* res; float* out; int g;
  int r2;
  if (row < TENC) { res = res_e; out = out_e; g = gate_e; r2 = row; }
  else            { res = res_h; out = out_h; g = gate_h; r2 = row - TENC; }
  f32x4 g4 = *(const f32x4*)(emb + (size_t)g * D + col);
  f32x4 rr4 = *(const f32x4*)(res + (size_t)r2 * D + col);
  f32x4 o;
  #pragma unroll
  for (int j = 0; j < 4; ++j) o[j] = rr4[j] + s[j] * g4[j];
  *(f32x4*)(out + (size_t)r2 * D + col) = o;
}

// ---------------- split-K reduce + gate + residual -> h1/e1 f32, THEN LN+mod -> xln bf16
template<int P>
__global__ __launch_bounds__(256) void redk_ln(
    const float* __restrict__ parts, const float* __restrict__ bias,
    const float* __restrict__ emb, int gate_h, int gate_e,
    int shift_h, int scale_h, int shift_e, int scale_e,
    const float* __restrict__ res_h, const float* __restrict__ res_e,
    float* __restrict__ out_h, float* __restrict__ out_e, bf16_t* __restrict__ xout) {
  int row = blockIdx.x, tid = threadIdx.x;
  const float* res; float* out; int g, sh, sc; int r2;
  if (row < TENC) { res = res_e; out = out_e; g = gate_e; sh = shift_e; sc = scale_e; r2 = row; }
  else            { res = res_h; out = out_h; g = gate_h; sh = shift_h; sc = scale_h; r2 = row - TENC; }
  float v[10], s = 0.f, s2 = 0.f;
  #pragma unroll
  for (int i = 0; i < 10; ++i) {
    int c = tid + i * 256;
    float val = bias[c];
    #pragma unroll
    for (int p = 0; p < P; ++p) val += parts[(size_t)p * SEQ * D + (size_t)row * D + c];
    val = res[(size_t)r2 * D + c] + val * emb[(size_t)g * D + c];
    out[(size_t)r2 * D + c] = val;
    v[i] = val; s += val; s2 += val * val;
  }
  #pragma unroll
  for (int o = 32; o > 0; o >>= 1) { s += __shfl_down(s, o); s2 += __shfl_down(s2, o); }
  __shared__ float red[8];
  int wvv = tid >> 6, lnn = tid & 63;
  if (lnn == 0) { red[wvv] = s; red[4 + wvv] = s2; }
  __syncthreads();
  s  = red[0] + red[1] + red[2] + red[3];
  s2 = red[4] + red[5] + red[6] + red[7];
  float mean = s * (1.f / D);
  float rstd = rsqrtf(s2 * (1.f / D) - mean * mean + 1e-5f);
  #pragma unroll
  for (int i = 0; i < 10; ++i) {
    int c = tid + i * 256;
    xout[(size_t)row * D + c] =
        (bf16_t)((v[i] - mean) * rstd * (1.f + emb[(size_t)sc * D + c]) + emb[(size_t)sh * D + c]);
  }
}

// ---------------- attention (fixed-max softmax, MFMA denominator, 2 q-frags/wave)
// roles: [0,576) attn | [576,6976) w1T
__global__ __launch_bounds__(256) void attn_plus(
    const bf16_t* __restrict__ qb, const bf16_t* __restrict__ kb,
    const bf16_t* __restrict__ vt, bf16_t* __restrict__ obf,
    const float* __restrict__ w1, bf16_t* __restrict__ w1T) {
  __shared__ char smem[30720] __attribute__((aligned(16)));
  const int b = blockIdx.x;
  if (b >= 576) {
    int l = b - 576;
    wtrans_tile(w1, w1T, D, FFD, l % 40, l / 40, threadIdx.x, (float*)smem);
    return;
  }
  bf16_t* Ks = (bf16_t*)smem;                 // [64*64]  8 KB
  bf16_t* Vs = (bf16_t*)(smem + 8192);        // [48*64]  6 KB
  bf16_t* Ps = (bf16_t*)(smem + 14336);       // [8][16*64] 16 KB (wave*2+qf)
  const int h = b & 63;
  const int qblk = b >> 6;                    // 9 q-blocks of 128
  const int tid = threadIdx.x, wv = tid >> 6, ln = tid & 63;
  const int qbase = qblk * 128 + wv * 32;
  const int lr = ln & 15, lg = ln >> 4;

  bf16x8 af[2][2];
  #pragma unroll
  for (int qf = 0; qf < 2; ++qf) {
    const bf16_t* qp = qb + ((size_t)h * SEQ + qbase + qf * 16 + lr) * 64 + lg * 8;
    af[qf][0] = *(const bf16x8*)(qp);
    af[qf][1] = *(const bf16x8*)(qp + 32);
  }
  const f32x4 zero = {0.f, 0.f, 0.f, 0.f};
  f32x4 acc[2][3];
  #pragma unroll
  for (int qf = 0; qf < 2; ++qf) { acc[qf][0] = zero; acc[qf][1] = zero; acc[qf][2] = zero; }

  const bf16_t* kbh = kb + (size_t)h * SEQ * 64;
  const bf16_t* vth = vt + (size_t)h * 48 * SEQ;

  for (int kv0 = 0; kv0 < SEQ; kv0 += 64) {
    __syncthreads();
    #pragma unroll
    for (int i = 0; i < 2; ++i) {
      int g = wv * 2 + i;
      int slot = g * 64 + ln;
      int kr = slot >> 3, so = slot & 7;
      gld_lds16(kbh + (size_t)(kv0 + kr) * 64 + ((so ^ (kr & 7)) << 3), &Ks[g * 512]);
    }
    #pragma unroll
    for (int i = 0; i < 2; ++i) {
      int g = wv + 4 * i;
      if (g < 6) {
        int slot = g * 64 + ln;
        int dr = slot >> 3, so = slot & 7;
        gld_lds16(vth + (size_t)dr * SEQ + kv0 + ((so ^ (dr & 7)) << 3), &Vs[g * 512]);
      }
    }
    __syncthreads();
    #pragma unroll
    for (int nt = 0; nt < 4; ++nt) {
      int kvr = nt * 16 + lr;
      bf16x8 bk0 = *(const bf16x8*)&Ks[kvr * 64 + ((lg ^ (kvr & 7)) << 3)];
      bf16x8 bk1 = *(const bf16x8*)&Ks[kvr * 64 + (((4 + lg) ^ (kvr & 7)) << 3)];
      #pragma unroll
      for (int qf = 0; qf < 2; ++qf) {
        f32x4 s = zero;
        s = __builtin_amdgcn_mfma_f32_16x16x32_bf16(af[qf][0], bk0, s, 0, 0, 0);
        s = __builtin_amdgcn_mfma_f32_16x16x32_bf16(af[qf][1], bk1, s, 0, 0, 0);
        #pragma unroll
        for (int r = 0; r < 4; ++r) {
          float p = exp2f(fmaf(s[r], 1.44269504f, -9.377517766f));
          int q = lg * 4 + r;
          int kv = nt * 16 + lr;
          Ps[(wv * 2 + qf) * 1024 + q * 64 + ((((kv >> 3) ^ (q & 7)) << 3) | (kv & 7))] = (bf16_t)p;
        }
      }
    }
    bf16x8 pa[2][2];
    #pragma unroll
    for (int qf = 0; qf < 2; ++qf)
      #pragma unroll
      for (int kk = 0; kk < 2; ++kk)
        pa[qf][kk] = *(const bf16x8*)&Ps[(wv * 2 + qf) * 1024 + lr * 64 + (((kk * 4 + lg) ^ (lr & 7)) << 3)];
    #pragma unroll
    for (int dt = 0; dt < 3; ++dt) {
      int dr = dt * 16 + lr;
      #pragma unroll
      for (int kk = 0; kk < 2; ++kk) {
        bf16x8 bv = *(const bf16x8*)&Vs[dr * 64 + (((kk * 4 + lg) ^ (dr & 7)) << 3)];
        acc[0][dt] = __builtin_amdgcn_mfma_f32_16x16x32_bf16(pa[0][kk], bv, acc[0][dt], 0, 0, 0);
        acc[1][dt] = __builtin_amdgcn_mfma_f32_16x16x32_bf16(pa[1][kk], bv, acc[1][dt], 0, 0, 0);
      }
    }
  }
  #pragma unroll
  for (int qf = 0; qf < 2; ++qf) {
    float linv[4];
    #pragma unroll
    for (int r = 0; r < 4; ++r)
      linv[r] = 1.f / __shfl(acc[qf][2][r], (ln & 48) | 8);
    #pragma unroll
    for (int dt = 0; dt < 3; ++dt) {
      int d = dt * 16 + lr;
      if (d < HD) {
        #pragma unroll
        for (int r = 0; r < 4; ++r) {
          int q = qbase + qf * 16 + lg * 4 + r;
          obf[(size_t)q * D + h * HD + d] = (bf16_t)(acc[qf][dt][r] * linv[r]);
        }
      }
    }
  }
}

extern "C" void kernel_launch(void* const* d_in, const int* in_sizes, int n_in,
                              void* d_out, int out_size, void* d_ws, size_t ws_size,
                              hipStream_t stream) {
  const float* hid = (const float*)d_in[0];
  const float* enc = (const float*)d_in[1];
  const float* tem = (const float*)d_in[2];
  const float* rc  = (const float*)d_in[3];
  const float* rs  = (const float*)d_in[4];
  const float* aw  = (const float*)d_in[5];
  const float* ab  = (const float*)d_in[6];
  const float* wq  = (const float*)d_in[7];
  const float* bq  = (const float*)d_in[8];
  const float* wk  = (const float*)d_in[9];
  const float* bk  = (const float*)d_in[10];
  const float* wvv = (const float*)d_in[11];
  const float* bv  = (const float*)d_in[12];
  const float* wo  = (const float*)d_in[13];
  const float* bo  = (const float*)d_in[14];
  const float* w1  = (const float*)d_in[15];
  const float* b1  = (const float*)d_in[16];
  const float* w2  = (const float*)d_in[17];
  const float* b2  = (const float*)d_in[18];
  float* out_hid = (float*)d_out;
  float* out_enc = out_hid + (size_t)THID * D;

  char* ws = (char*)d_ws;
  size_t off = 0;
  auto alloc = [&](size_t b) { char* p = ws + off; off += (b + 255) & ~(size_t)255; return p; };
  float*  emb  = (float*) alloc((size_t)12 * D * 4);
  bf16_t* xln  = (bf16_t*)alloc((size_t)SEQ * D * 2);          // also attn-out bf16
  bf16_t* aff  = (bf16_t*)alloc((size_t)SEQ * FFD * 2);        // FF1 activation 23.6 MB
  bf16_t* vt   = (bf16_t*)alloc((size_t)NH * 48 * SEQ * 2);    // V^T bf16, d padded to 48 (row40=ones)
  bf16_t* qbb  = (bf16_t*)alloc((size_t)NH * SEQ * 64 * 2);    // Q bf16 padded; +kbb = h1/e1 after attn
  bf16_t* kbb  = (bf16_t*)alloc((size_t)NH * SEQ * 64 * 2);
  bf16_t* wqkvT= (bf16_t*)alloc((size_t)3 * D * D * 2);        // [7680][2560] 39.3 MB
  bf16_t* woT  = (bf16_t*)alloc((size_t)D * D * 2);            // 13.1 MB, after wqkvT
  bf16_t* w1T  = (bf16_t*)alloc((size_t)FFD * D * 2);          // 52.4 MB
  bf16_t* w2T  = (bf16_t*)alloc((size_t)D * FFD * 2);          // 52.4 MB
  float*  bqkv = (float*) alloc((size_t)3 * D * 4);
  bf16_t* obf = xln;
  float*  h1  = (float*)qbb;          // residual-1 hid (qbb/kbb dead after attn)
  float*  e1  = h1 + (size_t)THID * D;
  float*  qparts = (float*)w1T;       // QKV partials 70.8MB = w1T + first 18.4MB of w2T.
                                      //   Dead after L4; w1T/w2T written in L5/L6 (after).
  float*  oparts = (float*)wqkvT;     // O-proj partials 2x11.8MB, fits INSIDE wqkvT
  float*  fparts = (float*)wqkvT;     // FF2 partials 4x11.8MB (spills into woT -- dead by L9, OK)

  // L1: ada GEMV (480) + wq/wk/wv transposes (4800) + bcat (30) + vt pad (288)
  ada_plus<<<dim3(5598), dim3(256), 0, stream>>>(tem, aw, ab, emb,
      wq, wk, wvv, wqkvT, bq, bk, bv, bqkv, vt);
  // L2: LN+mod #1
  ln_mod<<<dim3(SEQ), dim3(256), 0, stream>>>(hid, enc, emb, xln, 0, 2, 1, 3);
  // L3: QKV GEMM split-K x2 (1080) + woT (1600) rider  [NO w2T here: qparts race]
  qkv_g<<<dim3(2680), dim3(256), 0, stream>>>(xln, wqkvT, qparts, wo, woT);
  // L4: QKV reduce + LN + RoPE + pack  (qparts dies here)
  qkv_red<<<dim3(SEQ), dim3(256), 0, stream>>>(qparts, bqkv, rc, rs, qbb, kbb, vt);
  // L5: attention (576, 2 q-frags/wave) + w1T (6400) rider
  attn_plus<<<dim3(6976), dim3(256), 0, stream>>>(qbb, kbb, vt, obf, w1, w1T);
  // L6: O-proj split-K x2 (360) + w2T (6400) rider
  oproj_plus<<<dim3(6760), dim3(256), 0, stream>>>(obf, woT, oparts, w2, w2T);
  // L7: reduce + gate + residual -> h1/e1, fused LN+mod #2 -> xln
  redk_ln<2><<<dim3(SEQ), dim3(256), 0, stream>>>(oparts, bo, emb, 4, 5, 6, 8, 7, 9,
      hid, enc, h1, e1, xln);
  // L8: FF1
  gemm4<1><<<dim3(720), dim3(256), 0, stream>>>(xln, w1T, b1, D, 40, FFD, 9, 720,
      aff, nullptr);
  // L9: FF2 split-K x4 -> partials
  gemm4<4><<<dim3(720), dim3(256), 0, stream>>>(aff, w2T, nullptr, FFD, 40, D, 9, 180,
      nullptr, fparts);
  // L10: final reduce + gate + residual -> d_out
  redk<4><<<dim3(2880), dim3(256), 0, stream>>>(fparts, b2, emb, 10, 11, h1, e1, out_hid, out_enc);
}

// Round 15
// 407.552 us; speedup vs baseline: 1.0673x; 1.0361x over previous
//
#include <hip/hip_runtime.h>
#include <stdint.h>

#define D 2560
#define NH 64
#define HD 40
#define TE_ 512
#define FFD 10240
#define TENC 128
#define THID 1024
#define SEQ 1152   // TENC + THID

typedef __bf16 bf16_t;
typedef __bf16 bf16x8 __attribute__((ext_vector_type(8)));
typedef __bf16 bf16x4 __attribute__((ext_vector_type(4)));
typedef float  f32x4  __attribute__((ext_vector_type(4)));

__device__ __forceinline__ void gld_lds16(const void* g, void* l) {
  __builtin_amdgcn_global_load_lds((__attribute__((address_space(1))) void*)(g),
                                   (__attribute__((address_space(3))) void*)(l), 16, 0, 0);
}

// ---------------- weight transpose+convert tile: W[K][N] f32 -> Wt[N][K] bf16
__device__ __forceinline__ void wtrans_tile(const float* __restrict__ W, bf16_t* __restrict__ Wt,
                                            int K, int N, int bk, int bn, int tid,
                                            float* tile /* 64*65 f32 */) {
  #pragma unroll
  for (int i = 0; i < 4; ++i) {
    int c = i * 256 + tid;             // 0..1023
    int r = c >> 4, q = c & 15;
    f32x4 v = *(const f32x4*)(W + (size_t)(bk * 64 + r) * N + bn * 64 + q * 4);
    tile[r * 65 + q * 4 + 0] = v[0]; tile[r * 65 + q * 4 + 1] = v[1];
    tile[r * 65 + q * 4 + 2] = v[2]; tile[r * 65 + q * 4 + 3] = v[3];
  }
  __syncthreads();
  #pragma unroll
  for (int i = 0; i < 2; ++i) {
    int c = i * 256 + tid;             // 0..511
    int n = c >> 3, kc = c & 7;
    bf16x8 o;
    #pragma unroll
    for (int j = 0; j < 8; ++j) o[j] = (bf16_t)tile[(kc * 8 + j) * 65 + n];
    *(bf16x8*)(Wt + (size_t)(bn * 64 + n) * K + bk * 64 + kc * 8) = o;
  }
}

// ---------------- ada_plus: ada GEMV + wq/wk/wv transposes + bcat + vt pad
// roles: [0,480) ada | [480,2080) wq | [2080,3680) wk | [3680,5280) wv
//        [5280,5310) bcat | [5310,5598) vt pad (row 40 = ONES, 41..47 zero)
__global__ __launch_bounds__(256) void ada_plus(
    const float* __restrict__ te, const float* __restrict__ aw,
    const float* __restrict__ ab, float* __restrict__ emb,
    const float* __restrict__ wq, const float* __restrict__ wk, const float* __restrict__ wv,
    bf16_t* __restrict__ wqkvT,
    const float* __restrict__ bq, const float* __restrict__ bk, const float* __restrict__ bv,
    float* __restrict__ bqkv, bf16_t* __restrict__ vt) {
  __shared__ float tile[64 * 65];
  const int b = blockIdx.x, t = threadIdx.x;
  if (b < 480) {
    float* red = tile;
    const int j = b * 64 + (t & 63);
    const int kc = t >> 6;
    const float* awp = aw + (size_t)(kc * 128) * (12 * D) + j;
    const float* tep = te + kc * 128;
    float a0 = 0.f, a1 = 0.f, a2 = 0.f, a3 = 0.f;
    #pragma unroll 8
    for (int k = 0; k < 128; k += 4) {
      a0 = fmaf(tep[k],     awp[(size_t)k * (12 * D)],       a0);
      a1 = fmaf(tep[k + 1], awp[(size_t)(k + 1) * (12 * D)], a1);
      a2 = fmaf(tep[k + 2], awp[(size_t)(k + 2) * (12 * D)], a2);
      a3 = fmaf(tep[k + 3], awp[(size_t)(k + 3) * (12 * D)], a3);
    }
    red[kc * 64 + (t & 63)] = (a0 + a1) + (a2 + a3);
    __syncthreads();
    if (t < 64)
      emb[j] = ab[j] + red[t] + red[64 + t] + red[128 + t] + red[192 + t];
  } else if (b < 2080) {
    int l = b - 480;  wtrans_tile(wq, wqkvT,                     D, D, l % 40, l / 40, t, tile);
  } else if (b < 3680) {
    int l = b - 2080; wtrans_tile(wk, wqkvT + (size_t)D * D,     D, D, l % 40, l / 40, t, tile);
  } else if (b < 5280) {
    int l = b - 3680; wtrans_tile(wv, wqkvT + (size_t)2 * D * D, D, D, l % 40, l / 40, t, tile);
  } else if (b < 5310) {
    int i = (b - 5280) * 256 + t;
    bqkv[i] = i < D ? bq[i] : (i < 2 * D ? bk[i - D] : bv[i - 2 * D]);
  } else {
    int i = (b - 5310) * 256 + t;      // 73728 granules = 64 heads * 1152, rows 40..47
    int h = i / 1152, g = i - h * 1152;
    bf16x8 z = {};
    if (g < 144) {                     // offsets [0,1152) = row 40 -> ones
      #pragma unroll
      for (int j = 0; j < 8; ++j) z[j] = (bf16_t)1.f;
    }
    *(bf16x8*)(vt + ((size_t)h * 48 + 40) * SEQ + g * 8) = z;
  }
}

// ---------------- LN + adaLN modulation -> bf16 x  (rows 0..127 = encoder)
__global__ void ln_mod(const float* __restrict__ hid, const float* __restrict__ enc,
                       const float* __restrict__ emb, bf16_t* __restrict__ out,
                       int shift_h, int scale_h, int shift_e, int scale_e) {
  int row = blockIdx.x, tid = threadIdx.x;
  const float *src, *sc, *sh;
  if (row < TENC) { src = enc + (size_t)row * D;          sc = emb + scale_e * D; sh = emb + shift_e * D; }
  else            { src = hid + (size_t)(row - TENC) * D; sc = emb + scale_h * D; sh = emb + shift_h * D; }
  float v[10], s = 0.f, s2 = 0.f;
  #pragma unroll
  for (int i = 0; i < 10; ++i) { v[i] = src[tid + i * 256]; s += v[i]; s2 += v[i] * v[i]; }
  #pragma unroll
  for (int o = 32; o > 0; o >>= 1) { s += __shfl_down(s, o); s2 += __shfl_down(s2, o); }
  __shared__ float red[8];
  int wv = tid >> 6, ln = tid & 63;
  if (ln == 0) { red[wv] = s; red[4 + wv] = s2; }
  __syncthreads();
  s  = red[0] + red[1] + red[2] + red[3];
  s2 = red[4] + red[5] + red[6] + red[7];
  float mean = s * (1.f / D);
  float rstd = rsqrtf(s2 * (1.f / D) - mean * mean + 1e-5f);
  #pragma unroll
  for (int i = 0; i < 10; ++i) {
    int c = tid + i * 256;
    out[(size_t)row * D + c] = (bf16_t)((v[i] - mean) * rstd * (1.f + sc[c]) + sh[c]);
  }
}

// ---------------- GEMM body (m97 structure): C[1152][N] = A_bf16 @ Bt_bf16^T
// EPI 1: gelu->bf16   EPI 4: f32 partial (no bias)   EPI 5: bf16 partial (no bias)
template<int EPI>
__device__ __forceinline__ void gemm_body(
    bf16_t* As, bf16_t* Bs,
    const bf16_t* __restrict__ A, const bf16_t* __restrict__ Bt,
    const float* __restrict__ bias, int Kld, int ksteps, int N, int nM, int nMN,
    int nwg, int orig,
    bf16_t* __restrict__ outb, float* __restrict__ outp) {
  const int q8 = nwg >> 3, r8 = nwg & 7;
  const int xcd = orig & 7, pos = orig >> 3;
  const int wg = (xcd < r8 ? xcd * (q8 + 1) : r8 * (q8 + 1) + (xcd - r8) * q8) + pos;
  const int part = wg / nMN, rest = wg - part * nMN;
  const int bm = rest % nM, bn = rest / nM;
  const int m0 = bm * 128, n0 = bn * 128;
  const int kbase = part * ksteps;
  const int tid = threadIdx.x, wv = tid >> 6, ln = tid & 63;
  const int wr = wv >> 1, wc = wv & 1, lr = ln & 15, lg = ln >> 4;

  f32x4 acc[4][4];
  const f32x4 zero = {0.f, 0.f, 0.f, 0.f};
  #pragma unroll
  for (int m = 0; m < 4; ++m)
    #pragma unroll
    for (int n = 0; n < 4; ++n) acc[m][n] = zero;

  for (int t = 0; t < ksteps; ++t) {
    const int k0 = (kbase + t) << 6;
    __syncthreads();
    #pragma unroll
    for (int i = 0; i < 4; ++i) {        // A: 128x64 = 16 chunks
      int g = wv * 4 + i;
      int s = g * 64 + ln;
      int r = s >> 3, ks = s & 7;
      gld_lds16(A + (size_t)(m0 + r) * Kld + k0 + ((ks ^ (r & 7)) << 3), &As[g * 512]);
    }
    #pragma unroll
    for (int i = 0; i < 4; ++i) {        // Bt: 128x64 = 16 chunks
      int g = wv * 4 + i;
      int s = g * 64 + ln;
      int r = s >> 3, ks = s & 7;
      gld_lds16(Bt + (size_t)(n0 + r) * Kld + k0 + ((ks ^ (r & 7)) << 3), &Bs[g * 512]);
    }
    __syncthreads();
    #pragma unroll
    for (int ks2 = 0; ks2 < 2; ++ks2) {
      int ko = ks2 * 4 + lg;
      bf16x8 af[4], bfr[4];
      #pragma unroll
      for (int m = 0; m < 4; ++m) {
        int r = wr * 64 + m * 16 + lr;
        af[m] = *(const bf16x8*)&As[r * 64 + ((ko ^ (r & 7)) << 3)];
      }
      #pragma unroll
      for (int n = 0; n < 4; ++n) {
        int c = wc * 64 + n * 16 + lr;
        bfr[n] = *(const bf16x8*)&Bs[c * 64 + ((ko ^ (c & 7)) << 3)];
      }
      #pragma unroll
      for (int m = 0; m < 4; ++m)
        #pragma unroll
        for (int n = 0; n < 4; ++n)
          acc[m][n] = __builtin_amdgcn_mfma_f32_16x16x32_bf16(af[m], bfr[n], acc[m][n], 0, 0, 0);
    }
  }

  #pragma unroll
  for (int m = 0; m < 4; ++m) {
    int row = m0 + wr * 64 + m * 16 + (lg << 2);
    #pragma unroll
    for (int n = 0; n < 4; ++n) {
      int col = n0 + wc * 64 + n * 16 + lr;
      float bv = (EPI == 4 || EPI == 5) ? 0.f : bias[col];
      #pragma unroll
      for (int r = 0; r < 4; ++r) {
        float val = acc[m][n][r] + bv;
        int rr = row + r;
        if (EPI == 1) {
          float z = 0.7978845608028654f * (val + 0.044715f * val * val * val);
          float t2 = 1.f - 2.f / (__expf(2.f * z) + 1.f);
          outb[(size_t)rr * N + col] = (bf16_t)(0.5f * val * (1.f + t2));
        } else if (EPI == 5) {
          outb[(size_t)part * SEQ * N + (size_t)rr * N + col] = (bf16_t)val;
        } else {
          outp[(size_t)part * SEQ * N + (size_t)rr * N + col] = val;
        }
      }
    }
  }
}

template<int EPI>
__global__ __launch_bounds__(256, 4) void gemm4(
    const bf16_t* __restrict__ A, const bf16_t* __restrict__ Bt,
    const float* __restrict__ bias, int Kld, int ksteps, int N, int nM, int nMN,
    bf16_t* __restrict__ outb, float* __restrict__ outp) {
  __shared__ bf16_t As[128 * 64];
  __shared__ bf16_t Bs[128 * 64];
  gemm_body<EPI>(As, Bs, A, Bt, bias, Kld, ksteps, N, nM, nMN, gridDim.x, blockIdx.x,
                 outb, outp);
}

// ---------------- QKV GEMM (split-K x2, bf16 partials) + woT transpose riding
// roles: [0,1080) gemm | [1080,2680) woT (40x40 tiles)
// qparts (bf16, 35.4MB) fits entirely inside w1T (written later, L5) -> alias-safe.
__global__ __launch_bounds__(256, 4) void qkv_g(
    const bf16_t* __restrict__ A, const bf16_t* __restrict__ wqkvT,
    bf16_t* __restrict__ qparts,
    const float* __restrict__ wo, bf16_t* __restrict__ woT) {
  __shared__ char smem[32768] __attribute__((aligned(16)));
  const int b = blockIdx.x;
  if (b < 1080) {
    gemm_body<5>((bf16_t*)smem, (bf16_t*)(smem + 16384), A, wqkvT, nullptr,
                 D, 20, 3 * D, 9, 540, 1080, b, qparts, nullptr);
  } else {
    int l = b - 1080;
    wtrans_tile(wo, woT, D, D, l % 40, l / 40, threadIdx.x, (float*)smem);
  }
}

// ---------------- O-proj GEMM (split-K x2, f32 partials) + w2T transpose riding
// roles: [0,360) gemm | [360,6760) w2T (160x40 tiles)
__global__ __launch_bounds__(256, 4) void oproj_plus(
    const bf16_t* __restrict__ A, const bf16_t* __restrict__ woT,
    float* __restrict__ oparts,
    const float* __restrict__ w2, bf16_t* __restrict__ w2T) {
  __shared__ char smem[32768] __attribute__((aligned(16)));
  const int b = blockIdx.x;
  if (b < 360) {
    gemm_body<4>((bf16_t*)smem, (bf16_t*)(smem + 16384), A, woT, nullptr,
                 D, 20, D, 9, 180, 360, b, nullptr, oparts);
  } else {
    int l = b - 360;
    wtrans_tile(w2, w2T, FFD, D, l % 160, l / 160, threadIdx.x, (float*)smem);
  }
}

// ---------------- qkv_red: sum bf16 partials + bias + per-head LN + RoPE -> qbb/kbb, V -> vt
__global__ __launch_bounds__(256) void qkv_red(
    const bf16_t* __restrict__ parts, const float* __restrict__ bqkv,
    const float* __restrict__ rc, const float* __restrict__ rs,
    bf16_t* __restrict__ qb, bf16_t* __restrict__ kb, bf16_t* __restrict__ vt) {
  const int r = blockIdx.x, t = threadIdx.x;
  const int h = t >> 2, sub = t & 3;
  __shared__ float cs_s[HD], sn_s[HD];
  const bool rope = (r >= TENC);
  if (rope && t < 2 * HD) {
    if (t < HD) cs_s[t] = rc[(size_t)(r - TENC) * HD + t];
    else        sn_s[t - HD] = rs[(size_t)(r - TENC) * HD + (t - HD)];
  }
  const bf16_t* p0 = parts + (size_t)r * (3 * D);
  const bf16_t* p1 = p0 + (size_t)SEQ * (3 * D);
  const int cq = h * HD + sub * 10;
  float q[10], k[10], v[10];
  #pragma unroll
  for (int j = 0; j < 10; ++j) {
    q[j] = (float)p0[cq + j] + (float)p1[cq + j] + bqkv[cq + j];
    k[j] = (float)p0[D + cq + j] + (float)p1[D + cq + j] + bqkv[D + cq + j];
    v[j] = (float)p0[2 * D + cq + j] + (float)p1[2 * D + cq + j] + bqkv[2 * D + cq + j];
  }
  __syncthreads();
  float qs = 0.f, qs2 = 0.f, ks = 0.f, ks2 = 0.f;
  #pragma unroll
  for (int j = 0; j < 10; ++j) { qs += q[j]; qs2 += q[j] * q[j]; ks += k[j]; ks2 += k[j] * k[j]; }
  qs += __shfl_xor(qs, 1); qs += __shfl_xor(qs, 2);
  qs2 += __shfl_xor(qs2, 1); qs2 += __shfl_xor(qs2, 2);
  ks += __shfl_xor(ks, 1); ks += __shfl_xor(ks, 2);
  ks2 += __shfl_xor(ks2, 1); ks2 += __shfl_xor(ks2, 2);
  float qm = qs * (1.f / HD), km = ks * (1.f / HD);
  float qr = rsqrtf(qs2 * (1.f / HD) - qm * qm + 1e-5f);
  float kr = rsqrtf(ks2 * (1.f / HD) - km * km + 1e-5f);
  #pragma unroll
  for (int j = 0; j < 10; ++j) { q[j] = (q[j] - qm) * qr; k[j] = (k[j] - km) * kr; }
  if (rope) {
    float pq[10], pk[10];
    #pragma unroll
    for (int j = 0; j < 10; ++j) { pq[j] = __shfl_xor(q[j], 2); pk[j] = __shfl_xor(k[j], 2); }
    #pragma unroll
    for (int j = 0; j < 10; ++j) {
      int d = sub * 10 + j;
      float c = cs_s[d], s = sn_s[d];
      if (d < 20) { q[j] = q[j] * c - pq[j] * s; k[j] = k[j] * c - pk[j] * s; }
      else        { q[j] = q[j] * c + pq[j] * s; k[j] = k[j] * c + pk[j] * s; }
    }
  }
  bf16_t* qd = qb + ((size_t)h * SEQ + r) * 64;
  bf16_t* kd = kb + ((size_t)h * SEQ + r) * 64;
  const float qscale = 0.15811388300841897f;  // 1/sqrt(40)
  #pragma unroll
  for (int j = 0; j < 10; ++j) {
    int d = sub * 10 + j;
    qd[d] = (bf16_t)(q[j] * qscale);
    kd[d] = (bf16_t)k[j];
  }
  #pragma unroll
  for (int j = 0; j < 6; ++j) {
    int d = 40 + sub * 6 + j;
    qd[d] = (bf16_t)0.f; kd[d] = (bf16_t)0.f;
  }
  #pragma unroll
  for (int j = 0; j < 10; ++j) {
    int d = sub * 10 + j;
    vt[((size_t)h * 48 + d) * SEQ + r] = (bf16_t)v[j];
  }
}

// ---------------- split-K reduce (bf16 partials) + bias + gate + residual -> f32 out
template<int P>
__global__ void redk_bf(const bf16_t* __restrict__ parts, const float* __restrict__ bias,
                        const float* __restrict__ emb, int gate_h, int gate_e,
                        const float* __restrict__ res_h, const float* __restrict__ res_e,
                        float* __restrict__ out_h, float* __restrict__ out_e) {
  int idx = blockIdx.x * 256 + threadIdx.x;      // over SEQ*D/4
  int row = idx / (D / 4), col = (idx - row * (D / 4)) * 4;
  f32x4 s = *(const f32x4*)(bias + col);
  #pragma unroll
  for (int p = 0; p < P; ++p) {
    bf16x4 b4 = *(const bf16x4*)(parts + (size_t)p * SEQ * D + (size_t)row * D + col);
    #pragma unroll
    for (int j = 0; j < 4; ++j) s[j] += (float)b4[j];
  }
  const float* res; float* out; int g;
  int r2;
  if (row < TENC) { res = res_e; out = out_e; g = gate_e; r2 = row; }
  else            { res = res_h; out = out_h; g = gate_h; r2 = row - TENC; }
  f32x4 g4 = *(const f32x4*)(emb + (size_t)g * D + col);
  f32x4 rr4 = *(const f32x4*)(res + (size_t)r2 * D + col);
  f32x4 o;
  #pragma unroll
  for (int j = 0; j < 4; ++j) o[j] = rr4[j] + s[j] * g4[j];
  *(f32x4*)(out + (size_t)r2 * D + col) = o;
}

// ---------------- split-K reduce (f32) + gate + residual -> h1/e1, THEN LN+mod -> xln bf16
template<int P>
__global__ __launch_bounds__(256) void redk_ln(
    const float* __restrict__ parts, const float* __restrict__ bias,
    const float* __restrict__ emb, int gate_h, int gate_e,
    int shift_h, int scale_h, int shift_e, int scale_e,
    const float* __restrict__ res_h, const float* __restrict__ res_e,
    float* __restrict__ out_h, float* __restrict__ out_e, bf16_t* __restrict__ xout) {
  int row = blockIdx.x, tid = threadIdx.x;
  const float* res; float* out; int g, sh, sc; int r2;
  if (row < TENC) { res = res_e; out = out_e; g = gate_e; sh = shift_e; sc = scale_e; r2 = row; }
  else            { res = res_h; out = out_h; g = gate_h; sh = shift_h; sc = scale_h; r2 = row - TENC; }
  float v[10], s = 0.f, s2 = 0.f;
  #pragma unroll
  for (int i = 0; i < 10; ++i) {
    int c = tid + i * 256;
    float val = bias[c];
    #pragma unroll
    for (int p = 0; p < P; ++p) val += parts[(size_t)p * SEQ * D + (size_t)row * D + c];
    val = res[(size_t)r2 * D + c] + val * emb[(size_t)g * D + c];
    out[(size_t)r2 * D + c] = val;
    v[i] = val; s += val; s2 += val * val;
  }
  #pragma unroll
  for (int o = 32; o > 0; o >>= 1) { s += __shfl_down(s, o); s2 += __shfl_down(s2, o); }
  __shared__ float red[8];
  int wvv = tid >> 6, lnn = tid & 63;
  if (lnn == 0) { red[wvv] = s; red[4 + wvv] = s2; }
  __syncthreads();
  s  = red[0] + red[1] + red[2] + red[3];
  s2 = red[4] + red[5] + red[6] + red[7];
  float mean = s * (1.f / D);
  float rstd = rsqrtf(s2 * (1.f / D) - mean * mean + 1e-5f);
  #pragma unroll
  for (int i = 0; i < 10; ++i) {
    int c = tid + i * 256;
    xout[(size_t)row * D + c] =
        (bf16_t)((v[i] - mean) * rstd * (1.f + emb[(size_t)sc * D + c]) + emb[(size_t)sh * D + c]);
  }
}

// ---------------- attention (fixed-max softmax, MFMA denominator, 2 q-frags/wave)
// roles: [0,576) attn | [576,6976) w1T
__global__ __launch_bounds__(256) void attn_plus(
    const bf16_t* __restrict__ qb, const bf16_t* __restrict__ kb,
    const bf16_t* __restrict__ vt, bf16_t* __restrict__ obf,
    const float* __restrict__ w1, bf16_t* __restrict__ w1T) {
  __shared__ char smem[30720] __attribute__((aligned(16)));
  const int b = blockIdx.x;
  if (b >= 576) {
    int l = b - 576;
    wtrans_tile(w1, w1T, D, FFD, l % 40, l / 40, threadIdx.x, (float*)smem);
    return;
  }
  bf16_t* Ks = (bf16_t*)smem;                 // [64*64]  8 KB
  bf16_t* Vs = (bf16_t*)(smem + 8192);        // [48*64]  6 KB
  bf16_t* Ps = (bf16_t*)(smem + 14336);       // [8][16*64] 16 KB (wave*2+qf)
  const int h = b & 63;
  const int qblk = b >> 6;                    // 9 q-blocks of 128
  const int tid = threadIdx.x, wv = tid >> 6, ln = tid & 63;
  const int qbase = qblk * 128 + wv * 32;
  const int lr = ln & 15, lg = ln >> 4;

  bf16x8 af[2][2];
  #pragma unroll
  for (int qf = 0; qf < 2; ++qf) {
    const bf16_t* qp = qb + ((size_t)h * SEQ + qbase + qf * 16 + lr) * 64 + lg * 8;
    af[qf][0] = *(const bf16x8*)(qp);
    af[qf][1] = *(const bf16x8*)(qp + 32);
  }
  const f32x4 zero = {0.f, 0.f, 0.f, 0.f};
  f32x4 acc[2][3];
  #pragma unroll
  for (int qf = 0; qf < 2; ++qf) { acc[qf][0] = zero; acc[qf][1] = zero; acc[qf][2] = zero; }

  const bf16_t* kbh = kb + (size_t)h * SEQ * 64;
  const bf16_t* vth = vt + (size_t)h * 48 * SEQ;

  for (int kv0 = 0; kv0 < SEQ; kv0 += 64) {
    __syncthreads();
    #pragma unroll
    for (int i = 0; i < 2; ++i) {
      int g = wv * 2 + i;
      int slot = g * 64 + ln;
      int kr = slot >> 3, so = slot & 7;
      gld_lds16(kbh + (size_t)(kv0 + kr) * 64 + ((so ^ (kr & 7)) << 3), &Ks[g * 512]);
    }
    #pragma unroll
    for (int i = 0; i < 2; ++i) {
      int g = wv + 4 * i;
      if (g < 6) {
        int slot = g * 64 + ln;
        int dr = slot >> 3, so = slot & 7;
        gld_lds16(vth + (size_t)dr * SEQ + kv0 + ((so ^ (dr & 7)) << 3), &Vs[g * 512]);
      }
    }
    __syncthreads();
    #pragma unroll
    for (int nt = 0; nt < 4; ++nt) {
      int kvr = nt * 16 + lr;
      bf16x8 bk0 = *(const bf16x8*)&Ks[kvr * 64 + ((lg ^ (kvr & 7)) << 3)];
      bf16x8 bk1 = *(const bf16x8*)&Ks[kvr * 64 + (((4 + lg) ^ (kvr & 7)) << 3)];
      #pragma unroll
      for (int qf = 0; qf < 2; ++qf) {
        f32x4 s = zero;
        s = __builtin_amdgcn_mfma_f32_16x16x32_bf16(af[qf][0], bk0, s, 0, 0, 0);
        s = __builtin_amdgcn_mfma_f32_16x16x32_bf16(af[qf][1], bk1, s, 0, 0, 0);
        #pragma unroll
        for (int r = 0; r < 4; ++r) {
          float p = exp2f(fmaf(s[r], 1.44269504f, -9.377517766f));
          int q = lg * 4 + r;
          int kv = nt * 16 + lr;
          Ps[(wv * 2 + qf) * 1024 + q * 64 + ((((kv >> 3) ^ (q & 7)) << 3) | (kv & 7))] = (bf16_t)p;
        }
      }
    }
    bf16x8 pa[2][2];
    #pragma unroll
    for (int qf = 0; qf < 2; ++qf)
      #pragma unroll
      for (int kk = 0; kk < 2; ++kk)
        pa[qf][kk] = *(const bf16x8*)&Ps[(wv * 2 + qf) * 1024 + lr * 64 + (((kk * 4 + lg) ^ (lr & 7)) << 3)];
    #pragma unroll
    for (int dt = 0; dt < 3; ++dt) {
      int dr = dt * 16 + lr;
      #pragma unroll
      for (int kk = 0; kk < 2; ++kk) {
        bf16x8 bv = *(const bf16x8*)&Vs[dr * 64 + (((kk * 4 + lg) ^ (dr & 7)) << 3)];
        acc[0][dt] = __builtin_amdgcn_mfma_f32_16x16x32_bf16(pa[0][kk], bv, acc[0][dt], 0, 0, 0);
        acc[1][dt] = __builtin_amdgcn_mfma_f32_16x16x32_bf16(pa[1][kk], bv, acc[1][dt], 0, 0, 0);
      }
    }
  }
  #pragma unroll
  for (int qf = 0; qf < 2; ++qf) {
    float linv[4];
    #pragma unroll
    for (int r = 0; r < 4; ++r)
      linv[r] = 1.f / __shfl(acc[qf][2][r], (ln & 48) | 8);
    #pragma unroll
    for (int dt = 0; dt < 3; ++dt) {
      int d = dt * 16 + lr;
      if (d < HD) {
        #pragma unroll
        for (int r = 0; r < 4; ++r) {
          int q = qbase + qf * 16 + lg * 4 + r;
          obf[(size_t)q * D + h * HD + d] = (bf16_t)(acc[qf][dt][r] * linv[r]);
        }
      }
    }
  }
}

extern "C" void kernel_launch(void* const* d_in, const int* in_sizes, int n_in,
                              void* d_out, int out_size, void* d_ws, size_t ws_size,
                              hipStream_t stream) {
  const float* hid = (const float*)d_in[0];
  const float* enc = (const float*)d_in[1];
  const float* tem = (const float*)d_in[2];
  const float* rc  = (const float*)d_in[3];
  const float* rs  = (const float*)d_in[4];
  const float* aw  = (const float*)d_in[5];
  const float* ab  = (const float*)d_in[6];
  const float* wq  = (const float*)d_in[7];
  const float* bq  = (const float*)d_in[8];
  const float* wk  = (const float*)d_in[9];
  const float* bk  = (const float*)d_in[10];
  const float* wvv = (const float*)d_in[11];
  const float* bv  = (const float*)d_in[12];
  const float* wo  = (const float*)d_in[13];
  const float* bo  = (const float*)d_in[14];
  const float* w1  = (const float*)d_in[15];
  const float* b1  = (const float*)d_in[16];
  const float* w2  = (const float*)d_in[17];
  const float* b2  = (const float*)d_in[18];
  float* out_hid = (float*)d_out;
  float* out_enc = out_hid + (size_t)THID * D;

  char* ws = (char*)d_ws;
  size_t off = 0;
  auto alloc = [&](size_t b) { char* p = ws + off; off += (b + 255) & ~(size_t)255; return p; };
  float*  emb  = (float*) alloc((size_t)12 * D * 4);
  bf16_t* xln  = (bf16_t*)alloc((size_t)SEQ * D * 2);          // also attn-out bf16
  bf16_t* aff  = (bf16_t*)alloc((size_t)SEQ * FFD * 2);        // FF1 activation 23.6 MB
  bf16_t* vt   = (bf16_t*)alloc((size_t)NH * 48 * SEQ * 2);    // V^T bf16, d padded to 48 (row40=ones)
  bf16_t* qbb  = (bf16_t*)alloc((size_t)NH * SEQ * 64 * 2);    // Q bf16 padded; +kbb = h1/e1 after attn
  bf16_t* kbb  = (bf16_t*)alloc((size_t)NH * SEQ * 64 * 2);
  bf16_t* wqkvT= (bf16_t*)alloc((size_t)3 * D * D * 2);        // [7680][2560] 39.3 MB
  bf16_t* woT  = (bf16_t*)alloc((size_t)D * D * 2);            // 13.1 MB, after wqkvT
  bf16_t* w1T  = (bf16_t*)alloc((size_t)FFD * D * 2);          // 52.4 MB
  bf16_t* w2T  = (bf16_t*)alloc((size_t)D * FFD * 2);          // 52.4 MB
  float*  bqkv = (float*) alloc((size_t)3 * D * 4);
  bf16_t* obf = xln;
  float*  h1  = (float*)qbb;          // residual-1 hid (qbb/kbb dead after attn)
  float*  e1  = h1 + (size_t)THID * D;
  bf16_t* qparts = w1T;               // QKV bf16 partials 2x17.7MB = 35.4MB, fits INSIDE w1T
                                      //   (dead after L4; w1T written L5 -- after)
  float*  oparts = (float*)wqkvT;     // O-proj f32 partials 2x11.8MB, fits INSIDE wqkvT
  bf16_t* fparts = wqkvT;             // FF2 bf16 partials 4x5.9MB = 23.6MB, fits INSIDE wqkvT

  // L1: ada GEMV (480) + wq/wk/wv transposes (4800) + bcat (30) + vt pad (288)
  ada_plus<<<dim3(5598), dim3(256), 0, stream>>>(tem, aw, ab, emb,
      wq, wk, wvv, wqkvT, bq, bk, bv, bqkv, vt);
  // L2: LN+mod #1
  ln_mod<<<dim3(SEQ), dim3(256), 0, stream>>>(hid, enc, emb, xln, 0, 2, 1, 3);
  // L3: QKV GEMM split-K x2 (1080, bf16 partials) + woT (1600) rider
  qkv_g<<<dim3(2680), dim3(256), 0, stream>>>(xln, wqkvT, qparts, wo, woT);
  // L4: QKV reduce + LN + RoPE + pack  (qparts dies here)
  qkv_red<<<dim3(SEQ), dim3(256), 0, stream>>>(qparts, bqkv, rc, rs, qbb, kbb, vt);
  // L5: attention (576, 2 q-frags/wave) + w1T (6400) rider
  attn_plus<<<dim3(6976), dim3(256), 0, stream>>>(qbb, kbb, vt, obf, w1, w1T);
  // L6: O-proj split-K x2 (360, f32 partials) + w2T (6400) rider
  oproj_plus<<<dim3(6760), dim3(256), 0, stream>>>(obf, woT, oparts, w2, w2T);
  // L7: reduce + gate + residual -> h1/e1, fused LN+mod #2 -> xln
  redk_ln<2><<<dim3(SEQ), dim3(256), 0, stream>>>(oparts, bo, emb, 4, 5, 6, 8, 7, 9,
      hid, enc, h1, e1, xln);
  // L8: FF1
  gemm4<1><<<dim3(720), dim3(256), 0, stream>>>(xln, w1T, b1, D, 40, FFD, 9, 720,
      aff, nullptr);
  // L9: FF2 split-K x4 -> bf16 partials
  gemm4<5><<<dim3(720), dim3(256), 0, stream>>>(aff, w2T, nullptr, FFD, 40, D, 9, 180,
      fparts, nullptr);
  // L10: final reduce + gate + residual -> d_out
  redk_bf<4><<<dim3(2880), dim3(256), 0, stream>>>(fparts, b2, emb, 10, 11, h1, e1,
      out_hid, out_enc);
}